// Round 1
// baseline (208.585 us; speedup 1.0000x reference)
//
#include <hip/hip_runtime.h>

// ForexPrep: per row (T=8192): p = diff(x)/x[:-1]; scale = max|p| (row);
// pn = p/scale; ma = 7-window moving average of pn; out = stack([ma, x[:-7]], -1)
// Shapes: x (4096, 8192) f32  ->  out (4096, 8185, 2) f32.

constexpr int T_LEN = 8192;
constexpr int GAP_  = 7;
constexpr int OUTW  = T_LEN - GAP_;   // 8185 outputs per row
constexpr int NP    = T_LEN - 1;      // 8191 valid p values per row
constexpr int CH    = 32;             // outputs per thread
constexpr int NTHR  = 256;            // threads per block (one block per row)

__global__ __launch_bounds__(NTHR)
void forex_prep_kernel(const float* __restrict__ x, float* __restrict__ out,
                       int n_rows) {
    const int row = blockIdx.x;
    if (row >= n_rows) return;
    const int t  = threadIdx.x;
    const int j0 = t * CH;
    const float* __restrict__ xr = x + (size_t)row * T_LEN;

    // ---- Load x[j0 .. j0+39] into registers (10x float4); pad OOB with 1.0f.
    float xv[40];
#pragma unroll
    for (int q = 0; q < 10; ++q) {
        const int i = j0 + 4 * q;
        if (i + 3 < T_LEN) {
            const float4 v = *reinterpret_cast<const float4*>(xr + i);
            xv[4*q+0] = v.x; xv[4*q+1] = v.y; xv[4*q+2] = v.z; xv[4*q+3] = v.w;
        } else {
#pragma unroll
            for (int e = 0; e < 4; ++e) {
                const int ii = i + e;
                xv[4*q+e] = (ii < T_LEN) ? xr[ii] : 1.0f;
            }
        }
    }

    // ---- p[k] = x[j0+k+1]/x[j0+k] - 1, zeroed where index invalid.
    // Zeroing invalid p's is safe: they never contribute to a stored output,
    // and they can't raise the max (true scale > 0 on this data).
    float pv[CH + GAP_ - 1];   // 38 values: p[j0 .. j0+37]
#pragma unroll
    for (int k = 0; k < CH + GAP_ - 1; ++k) {
        const float r  = __builtin_amdgcn_rcpf(xv[k]);      // ~1 ulp
        const float pk = fmaf(xv[k+1], r, -1.0f);           // x1/x0 - 1
        pv[k] = (j0 + k < NP) ? pk : 0.0f;
    }

    // ---- Local max |p| over own chunk (k = 0..31 covers p[j0..j0+31]).
    float m = 0.0f;
#pragma unroll
    for (int k = 0; k < CH; ++k) m = fmaxf(m, fabsf(pv[k]));

    // ---- Block-wide max: wave butterfly reduce, then tiny LDS combine.
#pragma unroll
    for (int off = 32; off > 0; off >>= 1)
        m = fmaxf(m, __shfl_xor(m, off, 64));
    __shared__ float red[NTHR / 64];
    if ((t & 63) == 0) red[t >> 6] = m;
    __syncthreads();
    float scale = red[0];
#pragma unroll
    for (int wv = 1; wv < NTHR / 64; ++wv) scale = fmaxf(scale, red[wv]);

    const float inv = __builtin_amdgcn_rcpf(scale * (float)GAP_); // 1/(7*scale)

    // ---- Rolling 7-window sum over pv; store {ma, x[j]} as float2.
    float2* __restrict__ orow =
        reinterpret_cast<float2*>(out) + (size_t)row * OUTW;
    float w = pv[0] + pv[1] + pv[2] + pv[3] + pv[4] + pv[5] + pv[6];
#pragma unroll
    for (int k = 0; k < CH; ++k) {
        if (k > 0) w += pv[k + GAP_ - 1] - pv[k - 1];
        if (j0 + k < OUTW) orow[j0 + k] = make_float2(w * inv, xv[k]);
    }
}

extern "C" void kernel_launch(void* const* d_in, const int* in_sizes, int n_in,
                              void* d_out, int out_size, void* d_ws, size_t ws_size,
                              hipStream_t stream) {
    const float* x = (const float*)d_in[0];
    float* out = (float*)d_out;
    const int n_rows = in_sizes[0] / T_LEN;   // 4096
    dim3 grid(n_rows), block(NTHR);
    hipLaunchKernelGGL(forex_prep_kernel, grid, block, 0, stream, x, out, n_rows);
}

// Round 2
// 83.334 us; speedup vs baseline: 2.5030x; 2.5030x over previous
//
#include <hip/hip_runtime.h>

// ForexPrep: per row (T=8192): p = diff(x)/x[:-1]; scale = max|p| (row);
// pn = p/scale; ma = 7-window moving average; out[b,j] = {ma(j), x(j)}.
// x (4096, 8192) f32 -> out (4096, 8185, 2) f32.
//
// R1: coalesced float4 output stores. Row byte base = row*65480 ≡ 8 (mod 16)
// for odd rows, so pair-grouping shifts by s = row&1 (uniform per block).

constexpr int T_LEN = 8192;
constexpr int GAP_  = 7;
constexpr int OUTW  = T_LEN - GAP_;   // 8185
constexpr int NP    = T_LEN - 1;      // 8191
constexpr int NTHR  = 256;
constexpr int PAIRS = 4092;           // float4-pairs per row (2 outputs each)

__global__ __launch_bounds__(NTHR)
void forex_prep_kernel(const float* __restrict__ x, float* __restrict__ out,
                       int n_rows) {
    const int row = blockIdx.x;
    if (row >= n_rows) return;
    const int t = threadIdx.x;

    __shared__ float xs[T_LEN];        // 32 KB: the whole row
    __shared__ float red[NTHR / 64];

    const float* __restrict__ xr = x + (size_t)row * T_LEN;

    // ---- Stage row into LDS: 8 coalesced float4 loads per thread (1 KB/wave/inst).
#pragma unroll
    for (int i = 0; i < T_LEN / (4 * NTHR); ++i) {
        const int e = (i * NTHR + t) * 4;
        const float4 v = *reinterpret_cast<const float4*>(xr + e);
        *reinterpret_cast<float4*>(xs + e) = v;
    }
    __syncthreads();

    // ---- Phase 1: block max of |p|, p[k] = x[k+1]/x[k] - 1 (k < 8191).
    float m = 0.0f;
#pragma unroll
    for (int i = 0; i < T_LEN / NTHR; ++i) {
        const int k = i * NTHR + t;
        if (k < NP) {
            const float pk = fmaf(xs[k + 1], __builtin_amdgcn_rcpf(xs[k]), -1.0f);
            m = fmaxf(m, fabsf(pk));
        }
    }
#pragma unroll
    for (int off = 32; off > 0; off >>= 1)
        m = fmaxf(m, __shfl_xor(m, off, 64));
    if ((t & 63) == 0) red[t >> 6] = m;
    __syncthreads();
    const float scale = fmaxf(fmaxf(red[0], red[1]), fmaxf(red[2], red[3]));
    const float inv = __builtin_amdgcn_rcpf(scale * (float)GAP_);  // 1/(7*scale)

    // ---- Phase 2: aligned float4 stores of output pairs.
    const int s = row & 1;             // pair-grouping shift for 16B alignment
    float* __restrict__ ob = out + (size_t)row * (OUTW * 2);

#pragma unroll
    for (int i = 0; i < 16; ++i) {
        const int u = i * NTHR + t;    // consecutive lanes -> consecutive pairs
        if (u < PAIRS) {
            const int j = s + 2 * u;   // first output index of this pair
            float xv[9];
#pragma unroll
            for (int e = 0; e < 9; ++e) xv[e] = xs[j + e];
            float p[8];
#pragma unroll
            for (int e = 0; e < 8; ++e)
                p[e] = fmaf(xv[e + 1], __builtin_amdgcn_rcpf(xv[e]), -1.0f);
            const float w0 = p[0] + p[1] + p[2] + p[3] + p[4] + p[5] + p[6];
            const float w1 = w0 - p[0] + p[7];
            // byte addr = row*65480 + 8*s + 16*u  -> 16B aligned for s=row&1
            *reinterpret_cast<float4*>(ob + 2 * j) =
                make_float4(w0 * inv, xv[0], w1 * inv, xv[1]);
        }
    }

    // ---- Leftover single output (j=8184 for even rows, j=0 for odd rows).
    if (t == 0) {
        const int j = s ? 0 : (OUTW - 1);
        float w = 0.0f;
#pragma unroll
        for (int e = 0; e < GAP_; ++e)
            w += fmaf(xs[j + e + 1], __builtin_amdgcn_rcpf(xs[j + e]), -1.0f);
        *reinterpret_cast<float2*>(ob + 2 * j) = make_float2(w * inv, xs[j]);
    }
}

extern "C" void kernel_launch(void* const* d_in, const int* in_sizes, int n_in,
                              void* d_out, int out_size, void* d_ws, size_t ws_size,
                              hipStream_t stream) {
    const float* x = (const float*)d_in[0];
    float* out = (float*)d_out;
    const int n_rows = in_sizes[0] / T_LEN;   // 4096
    dim3 grid(n_rows), block(NTHR);
    hipLaunchKernelGGL(forex_prep_kernel, grid, block, 0, stream, x, out, n_rows);
}